// Round 3
// baseline (488.777 us; speedup 1.0000x reference)
//
#include <hip/hip_runtime.h>

#define NB 4
#define CIN 64
#define COUT 64
#define H 128
#define W 128
#define H2 256
#define W2 256
#define HROWS 22
#define HCOLS 38
#define HSTRD 41
#define NSTG 836          // HROWS*HCOLS staged halo px per channel

// ws layout (float units)
#define WS_P1   0         // per-tile partial sums  [4*64][128]
#define WS_P2   32768     // per-tile partial sumsq
#define WS_MU   65536
#define WS_RSTD 65792
#define WS_W    66048     // pre-transposed bf16 weights: ushort[32][64][32]

// ---------------------------------------------------------------------------
// Compile-time DISCO basis (replicates the numpy double-precision computation)
// ---------------------------------------------------------------------------
constexpr double csqrt(double x) {
    double g = x > 1.0 ? x : 1.0;
    for (int i = 0; i < 64; ++i) g = 0.5 * (g + x / g);
    return g;
}
constexpr double catan_pos(double x) {
    double f = 1.0;
    for (int i = 0; i < 6; ++i) { x = x / (1.0 + csqrt(1.0 + x * x)); f *= 2.0; }
    double x2 = x * x, s = 0.0, term = x;
    for (int n = 0; n < 10; ++n) { s += term / (2 * n + 1) * ((n & 1) ? -1.0 : 1.0); term *= x2; }
    return f * s;
}
constexpr double catan2c(double y, double x) {
    const double PI = 3.141592653589793;
    if (x == 0.0 && y == 0.0) return 0.0;
    double ax = x < 0 ? -x : x, ay = y < 0 ? -y : y;
    double a = (ax >= ay) ? catan_pos(ay / ax) : (PI / 2.0 - catan_pos(ax / ay));
    if (x < 0) a = PI - a;
    return (y < 0) ? -a : a;
}

struct PsiTab { double v[81][9]; };
constexpr PsiTab compute_psi() {
    PsiTab P{};
    const double hy = 1.0 / 256.0;
    const double rcut = 0.015;
    const double dr = 0.0075;
    const double PI = 3.141592653589793;
    const double TWO_PI = 6.283185307179586;
    const double dphi = PI / 2.0;
    for (int ky = 0; ky < 9; ++ky)
        for (int kx = 0; kx < 9; ++kx) {
            double dy = (double)(ky - 4) * hy;
            double dx = (double)(kx - 4) * hy;
            double r = csqrt(dy * dy + dx * dx);
            double phi = catan2c(dy, dx);
            if (phi < 0.0) phi += TWO_PI;
            for (int k = 0; k < 9; ++k) {
                int ir = (k == 0) ? 0 : ((k - 1) / 4 + 1);
                double ctr = ir * dr;
                double ad = r > ctr ? r - ctr : ctr - r;
                double rv = (ad <= dr && r <= rcut) ? 1.0 - ad / dr : 0.0;
                double val;
                if (k == 0) val = rv;
                else {
                    int ip = (k - 1) % 4;
                    double da = phi - ip * dphi; if (da < 0) da = -da;
                    double d2 = TWO_PI - da; if (d2 < da) da = d2;
                    double pv = (da <= dphi) ? 1.0 - da / dphi : 0.0;
                    val = rv * pv;
                }
                P.v[ky * 9 + kx][k] = val * (hy * hy);
            }
        }
    return P;
}

struct TapTab {
    int nt;
    int off[48];          // dy*HSTRD + dx (dword offset from thread base)
    float val[48][9];
    bool nz[48][9];
};
constexpr TapTab make_taps() {
    TapTab T{};
    PsiTab P = compute_psi();
    for (int ky = 0; ky < 9; ++ky)
        for (int kx = 0; kx < 9; ++kx) {
            int t = ky * 9 + kx;
            bool any = false;
            for (int k = 0; k < 9; ++k) if (P.v[t][k] != 0.0) any = true;
            if (!any) continue;
            int dy = ky - 4, dx = kx - 4;    // support guarantees |dy|,|dx| <= 3
            T.off[T.nt] = dy * HSTRD + dx;
            for (int k = 0; k < 9; ++k) {
                T.val[T.nt][k] = (float)P.v[t][k];
                T.nz[T.nt][k] = (P.v[t][k] != 0.0);
            }
            T.nt++;
        }
    return T;
}
constexpr TapTab TT = make_taps();
constexpr int NT = TT.nt;
static_assert(NT > 0 && NT <= 48, "tap table overflow");

using f32x4  = __attribute__((ext_vector_type(4))) float;
using bf16x8 = __attribute__((ext_vector_type(8))) short;

__device__ __forceinline__ unsigned short f2bf_rne(float f) {
    unsigned u = __float_as_uint(f);
    unsigned r = (u + 0x7fff + ((u >> 16) & 1)) >> 16;
    return (unsigned short)r;
}
// RTZ pack of two floats to one u32 of 2 bf16 (bias cancels in InstanceNorm)
__device__ __forceinline__ unsigned pkrtz(float a, float b) {
    return (__float_as_uint(a) >> 16) | (__float_as_uint(b) & 0xffff0000u);
}

// ---------------------------------------------------------------------------
// Setup: pre-transpose weights to bf16 wsW[g][o][32]  (kk = ch*16 + k, pads 0)
// ---------------------------------------------------------------------------
__global__ void setup_w(const float* __restrict__ wgt, float* __restrict__ ws) {
    unsigned short* wsW = (unsigned short*)(ws + WS_W);
    const int g = blockIdx.x;          // channel pair 0..31
    const int t = threadIdx.x;         // 256
    const int o = t >> 2;
    const int k0 = (t & 3) * 8;
#pragma unroll
    for (int j = 0; j < 8; ++j) {
        int kk = k0 + j;
        int ch = kk >> 4, k = kk & 15;
        float v = (k < 9) ? wgt[((size_t)o * CIN + 2 * g + ch) * 9 + k] : 0.f;
        wsW[g * 2048 + o * 32 + kk] = f2bf_rne(v);
    }
}

// ---------------------------------------------------------------------------
// Fused upsample + DISCO conv. Block = 16x32 px tile (512 px), 4 waves.
// Thread owns px pair (32r+c, 32r+c+16). Per channel: z via compile-time taps
// (ds_read2 pairs), RTZ bf16 pack, MFMA 16x16x32 over K=2ch x 16.
// ---------------------------------------------------------------------------
__global__ __launch_bounds__(256, 2) void conv_kernel(const float* __restrict__ img,
                                                      float* __restrict__ out,
                                                      float* __restrict__ ws) {
    __shared__ unsigned short zbuf[512][40];   // [px][k] bf16, pads zero
    __shared__ float halo[4][904];             // 2 pairs x 2 ch, 22x41
    __shared__ float red1[4][64], red2[4][64];

    const int tid  = threadIdx.x;
    const int bid  = blockIdx.x;
    const int n    = bid >> 7;
    const int tile = bid & 127;
    const int ty0  = (tile >> 3) << 4;     // 16 tile-rows
    const int tx0  = (tile & 7) << 5;      // 8 tile-cols (32 wide)

    const int r = tid >> 4, c = tid & 15;
    const int hbase = (r + 3) * HSTRD + (c + 3);
    const int px0 = 32 * r + c;
    const int wv  = tid >> 6;
    const int l   = tid & 63;
    const int a16 = l & 15;
    const int kseg = (l >> 4) * 8;

    const unsigned short* wsW = (const unsigned short*)(ws + WS_W);

    // zero zbuf once (pads stay zero; finite for MFMA since A-pads are 0)
    {
        uint4* zr = (uint4*)&zbuf[0][0];
#pragma unroll
        for (int j = 0; j < 10; ++j) zr[tid + j * 256] = make_uint4(0, 0, 0, 0);
    }

    // ---- per-thread staging metadata (reused across all 64 channels) ----
    const float cs = (float)(127.0 / 255.0);
    int sA0[4], sA1[4], sHI[4];
    float sFY[4], sFX[4];
    unsigned sFL[4];
    bool sOK[4];
#pragma unroll
    for (int j = 0; j < 4; ++j) {
        int e = tid + j * 256;
        sOK[j] = (e < NSTG);
        int hy = e / HCOLS, hx = e - hy * HCOLS;
        sHI[j] = hy * HSTRD + hx;
        int uy = ty0 - 3 + hy, ux = tx0 - 3 + hx;
        bool zf = ((unsigned)uy >= 256u) || ((unsigned)ux >= 256u);
        float syf = (float)uy * cs;
        float sxf = (float)ux * cs;
        int y0 = (int)syf; y0 = min(max(y0, 0), 127);
        int x0 = (int)sxf; x0 = min(max(x0, 0), 127);
        int y1 = min(y0 + 1, 127);
        int xb = min(x0, 126);
        bool selx = (x0 > 126);
        sFY[j] = syf - (float)y0;
        sFX[j] = sxf - (float)x0;
        sA0[j] = y0 * W + xb;
        sA1[j] = y1 * W + xb;
        sFL[j] = (zf ? 1u : 0u) | (selx ? 2u : 0u);
    }

    f32x4 acc[4][8];
#pragma unroll
    for (int m = 0; m < 4; ++m)
#pragma unroll
        for (int t = 0; t < 8; ++t) acc[m][t] = (f32x4){0.f, 0.f, 0.f, 0.f};

    // staging helpers
    float L[4][4];
    auto stg_load = [&](int ich) {
        const float* imc = img + ((size_t)(n * CIN + ich)) * (H * W);
#pragma unroll
        for (int j = 0; j < 4; ++j) {
            if (sOK[j]) {
                L[j][0] = imc[sA0[j]];
                L[j][1] = imc[sA0[j] + 1];
                L[j][2] = imc[sA1[j]];
                L[j][3] = imc[sA1[j] + 1];
            }
        }
    };
    auto stg_write = [&](float* hn) {
#pragma unroll
        for (int j = 0; j < 4; ++j) {
            if (sOK[j]) {
                unsigned fl = sFL[j];
                float fy = sFY[j], fx = sFX[j];
                float a00 = (fl & 2) ? L[j][1] : L[j][0];
                float a10 = (fl & 2) ? L[j][3] : L[j][2];
                float a01 = L[j][1], a11 = L[j][3];
                float t0 = a00 + fy * (a10 - a00);
                float t1 = a01 + fy * (a11 - a01);
                float v = t0 + fx * (t1 - t0);
                v = (fl & 1) ? 0.f : v;
                hn[sHI[j]] = v;
            }
        }
    };
    auto zphase = [&](const float* hb, int chslot) {
        float z0[9] = {0.f,0.f,0.f,0.f,0.f,0.f,0.f,0.f,0.f};
        float z1[9] = {0.f,0.f,0.f,0.f,0.f,0.f,0.f,0.f,0.f};
#pragma unroll
        for (int t = 0; t < NT; ++t) {
            float ha = hb[hbase + TT.off[t]];
            float hc = hb[hbase + TT.off[t] + 16];
#pragma unroll
            for (int k = 0; k < 9; ++k)
                if (TT.nz[t][k]) {
                    z0[k] = fmaf(TT.val[t][k], ha, z0[k]);
                    z1[k] = fmaf(TT.val[t][k], hc, z1[k]);
                }
        }
        unsigned* zr = (unsigned*)&zbuf[px0][chslot * 16];
        zr[0] = pkrtz(z0[0], z0[1]);
        zr[1] = pkrtz(z0[2], z0[3]);
        zr[2] = pkrtz(z0[4], z0[5]);
        zr[3] = pkrtz(z0[6], z0[7]);
        zr[4] = __float_as_uint(z0[8]) >> 16;
        unsigned* zs = (unsigned*)&zbuf[px0 + 16][chslot * 16];
        zs[0] = pkrtz(z1[0], z1[1]);
        zs[1] = pkrtz(z1[2], z1[3]);
        zs[2] = pkrtz(z1[4], z1[5]);
        zs[3] = pkrtz(z1[6], z1[7]);
        zs[4] = __float_as_uint(z1[8]) >> 16;
    };

    // prologue: stage pair 0 into halo[0], halo[1]
    stg_load(0);  stg_write(&halo[0][0]);
    stg_load(1);  stg_write(&halo[1][0]);

#pragma unroll 1
    for (int g = 0; g < 32; ++g) {
        __syncthreads();   // staging done; prev MFMA zbuf reads done
        const int cb = (g & 1) * 2;
        const int nb = ((g + 1) & 1) * 2;

        // A-fragments direct from global (L2-hot), issued early
        bf16x8 af[4];
        {
            const unsigned short* wp = wsW + g * 2048 + a16 * 32 + kseg;
#pragma unroll
            for (int m = 0; m < 4; ++m)
                af[m] = *(const bf16x8*)(wp + m * 512);
        }

        // ch0: issue loads -> zphase hides latency -> lerp+write
        if (g < 31) stg_load(2 * g + 2);
        zphase(&halo[cb][0], 0);
        if (g < 31) stg_write(&halo[nb][0]);
        // ch1
        if (g < 31) stg_load(2 * g + 3);
        zphase(&halo[cb + 1][0], 1);
        if (g < 31) stg_write(&halo[nb + 1][0]);

        __syncthreads();   // zbuf ready

        bf16x8 bf[8];
#pragma unroll
        for (int t = 0; t < 8; ++t)
            bf[t] = *(const bf16x8*)&zbuf[wv * 128 + t * 16 + a16][kseg];
#pragma unroll
        for (int m = 0; m < 4; ++m)
#pragma unroll
            for (int t = 0; t < 8; ++t)
                acc[m][t] = __builtin_amdgcn_mfma_f32_16x16x32_bf16(af[m], bf[t], acc[m][t], 0, 0, 0);
    }

    // ---- epilogue: instance-norm partials + store y ----
#pragma unroll
    for (int m = 0; m < 4; ++m) {
#pragma unroll
        for (int r4 = 0; r4 < 4; ++r4) {
            float s = 0.f, q = 0.f;
#pragma unroll
            for (int t = 0; t < 8; ++t) {
                float v = acc[m][t][r4];
                s += v; q = fmaf(v, v, q);
            }
#pragma unroll
            for (int msk = 1; msk < 16; msk <<= 1) {
                s += __shfl_xor(s, msk);
                q += __shfl_xor(q, msk);
            }
            if (a16 == 0) {
                int o = m * 16 + (l >> 4) * 4 + r4;
                red1[wv][o] = s;
                red2[wv][o] = q;
            }
        }
    }

    const size_t nbase = (size_t)n * COUT * (H2 * W2);
#pragma unroll
    for (int m = 0; m < 4; ++m)
#pragma unroll
        for (int t = 0; t < 8; ++t) {
            int Y = ty0 + wv * 4 + (t >> 1);
            int X = tx0 + (t & 1) * 16 + a16;
#pragma unroll
            for (int r4 = 0; r4 < 4; ++r4) {
                int o = m * 16 + (l >> 4) * 4 + r4;
                out[nbase + (size_t)o * (H2 * W2) + Y * W2 + X] = acc[m][t][r4];
            }
        }
    __syncthreads();
    if (tid < 64) {
        float S1 = red1[0][tid] + red1[1][tid] + red1[2][tid] + red1[3][tid];
        float S2 = red2[0][tid] + red2[1][tid] + red2[2][tid] + red2[3][tid];
        ws[WS_P1 + (n * COUT + tid) * 128 + tile] = S1;
        ws[WS_P2 + (n * COUT + tid) * 128 + tile] = S2;
    }
}

// ---------------------------------------------------------------------------
// Stats: reduce 128 tile-partials per (n,c)
// ---------------------------------------------------------------------------
__global__ void stats_kernel(float* __restrict__ ws) {
    const int co  = blockIdx.x;
    const int t   = threadIdx.x;   // 64
    float s1 = ws[WS_P1 + co * 128 + t] + ws[WS_P1 + co * 128 + t + 64];
    float s2 = ws[WS_P2 + co * 128 + t] + ws[WS_P2 + co * 128 + t + 64];
#pragma unroll
    for (int m = 1; m < 64; m <<= 1) { s1 += __shfl_xor(s1, m); s2 += __shfl_xor(s2, m); }
    if (t == 0) {
        const float inv = 1.f / 65536.f;
        float mu  = s1 * inv;
        float var = s2 * inv - mu * mu;
        ws[WS_MU + co]   = mu;
        ws[WS_RSTD + co] = 1.f / sqrtf(var + 1e-5f);
    }
}

// ---------------------------------------------------------------------------
// Normalize + LeakyReLU(0.2), in place on d_out
// ---------------------------------------------------------------------------
__global__ void norm_kernel(float* __restrict__ out, const float* __restrict__ ws) {
    const int total = NB * COUT * H2 * W2 / 4;
    for (int idx = blockIdx.x * blockDim.x + threadIdx.x; idx < total;
         idx += gridDim.x * blockDim.x) {
        int co = idx >> 14;
        float mu = ws[WS_MU + co];
        float rs = ws[WS_RSTD + co];
        float4 v = ((float4*)out)[idx];
        float* p = (float*)&v;
#pragma unroll
        for (int j = 0; j < 4; ++j) {
            float t = (p[j] - mu) * rs;
            p[j] = (t >= 0.f) ? t : 0.2f * t;
        }
        ((float4*)out)[idx] = v;
    }
}

extern "C" void kernel_launch(void* const* d_in, const int* in_sizes, int n_in,
                              void* d_out, int out_size, void* d_ws, size_t ws_size,
                              hipStream_t stream) {
    const float* img = (const float*)d_in[0];
    const float* wgt = (const float*)d_in[1];
    float* out = (float*)d_out;
    float* ws  = (float*)d_ws;

    setup_w<<<32, 256, 0, stream>>>(wgt, ws);
    conv_kernel<<<NB * 128, 256, 0, stream>>>(img, out, ws);
    stats_kernel<<<256, 64, 0, stream>>>(ws);
    norm_kernel<<<2048, 256, 0, stream>>>(out, ws);
}